// Round 4
// baseline (195.965 us; speedup 1.0000x reference)
//
#include <hip/hip_runtime.h>

// LBP uniform P=8 R=1 on (32,3,512,512) f32, zero-padded borders.
// R5: barrier-free register streaming. Post-mortem of R4 (LDS tile, 68us):
// hbm 2.9 TB/s (36%), VALU 31%, conflicts minor -> latency-bound from the
// __syncthreads convoy + load->quant->ds_write chains, NOT over-fetch
// (FETCH was already compulsory). R5 structure:
//   - one wave == one full-width 512x8 strip: lane i owns cols 8i..8i+7.
//     Loads AND stores perfectly coalesced dwordx4; column halo via 2
//     __shfl per row (lane 0/63 are the real image border -> exact 0 pad).
//     No edge loads, no LDS, no barrier.
//   - neighbor quantization eliminated: floor(fl(n*255)) >= q_c  <=>
//     fl(n*255) >= q_c  (q_c = floor(fl(c*255)) is an integer; same fp32
//     product as the reference -> bit-exact). Only centers get floorf;
//     clip(0,255) is a no-op for m in [0,255].
//   - software pipeline: row loads issued 3 iterations ahead of use,
//     rolling 3 m-rows live. All loops fully unrolled, static indices.

#define LBP_H 512
#define LBP_W 512
#define NPLANES 96           // 32 * 3
#define HSTRIP 8             // rows per wave-strip

typedef float f32x4 __attribute__((ext_vector_type(4)));

__global__ __launch_bounds__(256) void lbp_kernel(const float* __restrict__ x,
                                                  float* __restrict__ out) {
    const int wid   = ((blockIdx.x << 8) + threadIdx.x) >> 6;  // global wave id
    const int lane  = threadIdx.x & 63;
    const int plane = wid >> 6;          // 64 strips per plane
    const int strip = wid & 63;
    const int r0    = strip << 3;        // first output row of strip
    const int j0    = lane << 3;         // first col of this lane

    const float* base  = x   + (size_t)plane * (LBP_H * LBP_W) + j0;
    float*       obase = out + (size_t)plane * (LBP_H * LBP_W) + j0;

    f32x4 a[10], b[10];      // raw rows r0-1 .. r0+8 (0 when OOB)
    float m[10][8];          // fl(v*255)
    float lm[10], rm[10];    // column halos (0 at image border)

    // issue the pair of coalesced loads for input row index r (0..9)
    auto LOADROW = [&](int r) {
        const int gr = r0 - 1 + r;                 // wave-uniform
        if ((unsigned)gr < LBP_H) {
            const float* rp = base + (size_t)gr * LBP_W;
            a[r] = *(const f32x4*)rp;
            b[r] = *(const f32x4*)(rp + 4);
        } else {
            a[r] = (f32x4)(0.0f);
            b[r] = (f32x4)(0.0f);
        }
    };
    // premultiply + column-halo shuffles for row r
    auto PREP = [&](int r) {
        m[r][0] = a[r].x * 255.0f;  m[r][1] = a[r].y * 255.0f;
        m[r][2] = a[r].z * 255.0f;  m[r][3] = a[r].w * 255.0f;
        m[r][4] = b[r].x * 255.0f;  m[r][5] = b[r].y * 255.0f;
        m[r][6] = b[r].z * 255.0f;  m[r][7] = b[r].w * 255.0f;
        const float l = __shfl_up(m[r][7], 1);     // lane i-1 col 7
        const float rg = __shfl_down(m[r][0], 1);  // lane i+1 col 0
        lm[r] = (lane == 0)  ? 0.0f : l;           // true left image border
        rm[r] = (lane == 63) ? 0.0f : rg;          // true right image border
    };

    // ---- prologue: 5 row-loads in flight, prep first two rows ----
#pragma unroll
    for (int r = 0; r < 5; ++r) LOADROW(r);
    PREP(0);
    PREP(1);

    // ---- main: compute output row p from m[p], m[p+1], m[p+2] ----
#pragma unroll
    for (int p = 0; p < HSTRIP; ++p) {
        if (p + 5 < 10) LOADROW(p + 5);            // stay 3 rows ahead
        PREP(p + 2);

        f32x4 o1, o2;
#pragma unroll
        for (int c = 0; c < 8; ++c) {
            const float q = floorf(m[p + 1][c]);   // center, integer-valued
            const float n0 = (c == 0) ? lm[p]     : m[p][c - 1];     // (-1,-1)
            const float n1 = m[p][c];                                 // (-1, 0)
            const float n2 = (c == 7) ? rm[p]     : m[p][c + 1];     // (-1,+1)
            const float n3 = (c == 7) ? rm[p + 1] : m[p + 1][c + 1]; // ( 0,+1)
            const float n4 = (c == 7) ? rm[p + 2] : m[p + 2][c + 1]; // (+1,+1)
            const float n5 = m[p + 2][c];                             // (+1, 0)
            const float n6 = (c == 0) ? lm[p + 2] : m[p + 2][c - 1]; // (+1,-1)
            const float n7 = (c == 0) ? lm[p + 1] : m[p + 1][c - 1]; // ( 0,-1)

            unsigned msk = 0u;
            msk |= (n0 >= q) ?   1u : 0u;
            msk |= (n1 >= q) ?   2u : 0u;
            msk |= (n2 >= q) ?   4u : 0u;
            msk |= (n3 >= q) ?   8u : 0u;
            msk |= (n4 >= q) ?  16u : 0u;
            msk |= (n5 >= q) ?  32u : 0u;
            msk |= (n6 >= q) ?  64u : 0u;
            msk |= (n7 >= q) ? 128u : 0u;
            const unsigned rot = ((msk >> 1) | (msk << 7)) & 255u;
            const int trans = __popc(msk ^ rot);
            const int val = (trans <= 2) ? __popc(msk) : 9;
            const float ov = (float)val * (1.0f / 255.0f);
            if (c < 4) o1[c] = ov; else o2[c - 4] = ov;
        }

        float* op = obase + (size_t)(r0 + p) * LBP_W;
        __builtin_nontemporal_store(o1, (f32x4*)op);
        __builtin_nontemporal_store(o2, (f32x4*)(op + 4));
    }
}

extern "C" void kernel_launch(void* const* d_in, const int* in_sizes, int n_in,
                              void* d_out, int out_size, void* d_ws, size_t ws_size,
                              hipStream_t stream) {
    const float* x = (const float*)d_in[0];
    float* out = (float*)d_out;
    // 96 planes x 64 strips = 6144 waves = 393216 threads / 256 = 1536 blocks
    const int blocks = NPLANES * 64 / 4;
    lbp_kernel<<<blocks, 256, 0, stream>>>(x, out);
}

// Round 5
// 170.589 us; speedup vs baseline: 1.1488x; 1.1488x over previous
//
#include <hip/hip_runtime.h>

// LBP uniform P=8 R=1 on (32,3,512,512) f32, zero-padded borders.
// R6: champion-R3 structure (all clamped loads up front -> single vmcnt wait
// -> fully unrolled compute), footprint halved for residency.
// Post-mortem R5 (84us): VGPR=40 proved the compiler collapsed the rolling
// pipeline; 32B-stride lane layout broke load/store coalescing (WRITE 130MB
// vs 98 compulsory). R4 (68us): syncthreads convoy. R3 (~57us): best, but
// e[6][6]+v[6] ~ >64 VGPR -> only ~4 waves/SIMD resident.
// R6 changes vs R3:
//   - 2x4 tile per thread (8 px): m[4][6]=24 regs, 12 VMEM/thread,
//     __launch_bounds__(256,8) targets 8 waves/SIMD (VGPR<=64), 2x waves.
//   - neighbors skip floorf: floor(t)>=q <=> t>=q for integer q (center
//     floors only, 8 per thread). Bit-exact vs reference.
//   - row-OOB masking folded into the *255 multiply with a wave-uniform
//     scale (rs = row_valid ? 255 : 0) -> SALU select, no per-elem cndmask.
//   - stores: coalesced float4 nontemporal (lane-consecutive 16B).

#define LBP_H 512
#define LBP_W 512
#define NPLANES 96           // 32 * 3

typedef float f32x4 __attribute__((ext_vector_type(4)));

__global__ __launch_bounds__(256, 8) void lbp_kernel(const float* __restrict__ x,
                                                     float* __restrict__ out) {
    const int idx   = blockIdx.x * 256 + threadIdx.x;
    const int col4  = idx & 127;          // 0..127  (cols j0..j0+3)
    const int rowg  = (idx >> 7) & 255;   // 0..255  (rows r0..r0+1)
    const int plane = idx >> 15;          // 0..95
    const int j0 = col4 << 2;
    const int r0 = rowg << 1;

    const float* base  = x   + (size_t)plane * (LBP_H * LBP_W);
    float*       obase = out + (size_t)plane * (LBP_H * LBP_W);

    const int jm1 = (j0 > 0)         ? j0 - 1 : 0;          // clamped left col
    const int jp4 = (j0 + 4 < LBP_W) ? j0 + 4 : LBP_W - 1;  // clamped right col
    const bool lok = (j0 > 0);
    const bool rok = (j0 + 4 < LBP_W);

    // ---- phase 1: ALL 12 loads issued back-to-back, addresses clamped ----
    f32x4 v[4];
    float lf[4], rt[4];
#pragma unroll
    for (int r = 0; r < 4; ++r) {
        int ri  = r0 - 1 + r;
        int ric = ri < 0 ? 0 : (ri >= LBP_H ? LBP_H - 1 : ri);
        const float* rp = base + ric * LBP_W;
        v[r]  = *(const f32x4*)(rp + j0);   // aligned 16B, lane-coalesced
        lf[r] = rp[jm1];
        rt[r] = rp[jp4];
    }

    // ---- phase 2: m = value*255, row-mask folded into the scale ----
    // m[r][k]: fl(x*255) at input row r0-1+r, col j0-1+k (0 outside image).
    // Neighbors stay UNFLOORED: floor(t) >= q  <=>  t >= q for integer q.
    float m[4][6];
#pragma unroll
    for (int r = 0; r < 4; ++r) {
        const int ri = r0 - 1 + r;
        const bool rv = (unsigned)ri < LBP_H;      // wave-uniform (SALU)
        const float rs = rv ? 255.0f : 0.0f;
        m[r][0] = lok ? lf[r] * rs : 0.0f;
        m[r][1] = v[r].x * rs;
        m[r][2] = v[r].y * rs;
        m[r][3] = v[r].z * rs;
        m[r][4] = v[r].w * rs;
        m[r][5] = rok ? rt[r] * rs : 0.0f;
    }

    // ---- phase 3: 8 LBP codes, 2 coalesced nt stores ----
#pragma unroll
    for (int p = 0; p < 2; ++p) {             // output row r0+p
        f32x4 o;
#pragma unroll
        for (int c = 0; c < 4; ++c) {         // output col j0+c
            const float q = floorf(m[p + 1][c + 1]);   // center, integer
            // circular order: (-1,-1),(-1,0),(-1,1),(0,1),(1,1),(1,0),(1,-1),(0,-1)
            unsigned msk = 0u;
            msk |= (m[p    ][c    ] >= q) ?   1u : 0u;
            msk |= (m[p    ][c + 1] >= q) ?   2u : 0u;
            msk |= (m[p    ][c + 2] >= q) ?   4u : 0u;
            msk |= (m[p + 1][c + 2] >= q) ?   8u : 0u;
            msk |= (m[p + 2][c + 2] >= q) ?  16u : 0u;
            msk |= (m[p + 2][c + 1] >= q) ?  32u : 0u;
            msk |= (m[p + 2][c    ] >= q) ?  64u : 0u;
            msk |= (m[p + 1][c    ] >= q) ? 128u : 0u;
            const unsigned rot = ((msk >> 1) | (msk << 7)) & 255u;
            const int trans = __popc(msk ^ rot);
            const int val = (trans <= 2) ? __popc(msk) : 9;
            o[c] = (float)val * (1.0f / 255.0f);
        }
        __builtin_nontemporal_store(
            o, (f32x4*)(obase + (size_t)(r0 + p) * LBP_W + j0));
    }
}

extern "C" void kernel_launch(void* const* d_in, const int* in_sizes, int n_in,
                              void* d_out, int out_size, void* d_ws, size_t ws_size,
                              hipStream_t stream) {
    const float* x = (const float*)d_in[0];
    float* out = (float*)d_out;
    // 96 planes x 256 row-pairs x 128 col4 = 3,145,728 threads / 256 = 12288
    const int blocks = NPLANES * 256 * 128 / 256;
    lbp_kernel<<<blocks, 256, 0, stream>>>(x, out);
}